// Round 11
// baseline (636.302 us; speedup 1.0000x reference)
//
#include <hip/hip_runtime.h>
#include <hip/hip_cooperative_groups.h>
#include <math.h>

namespace cg = cooperative_groups;

// Problem constants
#define BATCH 256
#define IC    1152   // 32*6*6 input capsule positions
#define DD    8
#define OO    10
#define EE    16
#define CHUNK 9      // ijk per block
#define NCHUNK 128   // IC / CHUNK
#define NT    512    // 8 waves per block
#define BPB   128    // batches per block (wave w owns rows 16w..16w+15)
#define NBP   2      // BATCH / BPB
#define WPC   (OO * DD * EE)   // 1280 floats of W per ijk

// dynamic-LDS byte offsets (16B-aligned)
#define W_HI_OFF 0
#define W_LO_OFF 23040                  // CHUNK*160*8*2
#define X_HI_OFF 46080
#define X_LO_OFF 64512                  // + CHUNK*BPB*8*2 = 18432
#define ZPAD_OFF 82944
#define SMEM_BYTES 82960

typedef __attribute__((ext_vector_type(8))) short short8;  // 8 bf16 (4 VGPR)
typedef __attribute__((ext_vector_type(4))) float f32x4;   // MFMA C/D

__device__ __forceinline__ unsigned short f2bf(float f) {  // RNE fp32->bf16
    unsigned u = __float_as_uint(f);
    unsigned r = u + 0x7FFFu + ((u >> 16) & 1u);
    return (unsigned short)(r >> 16);
}
__device__ __forceinline__ float bf2f(unsigned short h) {
    return __uint_as_float(((unsigned)h) << 16);
}

// ONE cooperative persistent kernel: stage W+x (bf16 hi/lo, MFMA layout) into
// LDS ONCE, then run all 3 routing iterations + squash with grid.sync()
// between stages. r10 proved the MFMA formulation correct (absmax unchanged);
// r0-r10 proved per-pass staging (fetch+convert+scatter) is the ~45us/pass
// invariant -- it is iteration-invariant work paid 3x, eliminated here.
// Co-residency: 256 blocks x 512 thr, 83KB LDS -> exactly 1 block/CU;
// launch_bounds(512,2) caps VGPR at 256 (live ~170: no spill).
// MFMA packing (r10, HW-verified): lane-group g=lane>>4 supplies k=8g..8g+7;
// A={Wh,Wl,Wh,0}[g], B={Xh,Xh,Xl,0}[g] -> one 16x16x32 bf16 MFMA computes
// XhWh+XhWl+XlWh (err ~2^-18). D: col=lane&15=b, row=4*(lane>>4)+reg=e.
__global__ __launch_bounds__(NT, 2) void caps_mega_kernel(
    const float* __restrict__ x,       // [256][1152][8]
    const float* __restrict__ W,       // [1152][10][8][16]
    float* __restrict__ V,             // [256][10][16] accumulated v (ws)
    float* __restrict__ s_part,        // [NCHUNK][256][10][16] (ws)
    float* __restrict__ out)           // [256][10][16]
{
    extern __shared__ float4 smem4[];
    char* smem = (char*)smem4;
    unsigned short* w_hi = (unsigned short*)(smem + W_HI_OFF);
    unsigned short* w_lo = (unsigned short*)(smem + W_LO_OFF);
    unsigned short* x_hi = (unsigned short*)(smem + X_HI_OFF);
    unsigned short* x_lo = (unsigned short*)(smem + X_LO_OFF);
    unsigned short* zpad = (unsigned short*)(smem + ZPAD_OFF);

    const int tid  = threadIdx.x;
    const int wv   = tid >> 6;     // wave 0..7
    const int lane = tid & 63;
    const int q    = lane >> 4;    // k-group 0..3
    const int em   = lane & 15;    // A-row (e) / B-col (b-local)
    const int cx   = blockIdx.x;   // chunk 0..127
    const int bp   = blockIdx.y;   // batch half 0..1
    const int ijk0 = cx * CHUNK;
    const int bg0  = bp * BPB;
    const int bid  = bp * NCHUNK + cx;   // 0..255

    if (tid < 4) ((unsigned*)zpad)[tid] = 0u;

    // ---- stage W chunk ONCE: fp32 -> bf16 hi/lo, layout [s][o*16+e][d] ----
    {
        const float4* wg4 = reinterpret_cast<const float4*>(W + (size_t)ijk0 * WPC);
        #pragma unroll 1
        for (int f = tid; f < (CHUNK * WPC / 4); f += NT) {   // 2880 units
            const float4 t = wg4[f];
            const int l4 = f << 2;
            const int e0 = l4 & 15;
            int rr = l4 >> 4;
            const int d = rr & 7; rr >>= 3;
            const int o = rr % 10, s = rr / 10;
            const float vv[4] = {t.x, t.y, t.z, t.w};
            #pragma unroll
            for (int j = 0; j < 4; ++j) {
                const unsigned short h = f2bf(vv[j]);
                const unsigned short l = f2bf(vv[j] - bf2f(h));
                const int off = (s * 160 + o * 16 + e0 + j) * 8 + d;
                w_hi[off] = h; w_lo[off] = l;
            }
        }
    }
    // ---- stage x chunk ONCE: layout [s][b][d], b over 128 batches ----
    {
        #pragma unroll 1
        for (int ui = tid; ui < CHUNK * BPB; ui += NT) {      // 1152 rows
            const int b = ui / CHUNK, s = ui % CHUNK;         // s fastest: coalesced
            const float* xp = x + ((size_t)(bg0 + b) * IC + (ijk0 + s)) * DD;
            const float4 xa = *reinterpret_cast<const float4*>(xp);
            const float4 xb = *reinterpret_cast<const float4*>(xp + 4);
            const float vv[8] = {xa.x,xa.y,xa.z,xa.w, xb.x,xb.y,xb.z,xb.w};
            short8 hv, lv;
            #pragma unroll
            for (int j = 0; j < 8; ++j) {
                const unsigned short h = f2bf(vv[j]);
                hv[j] = (short)h;
                lv[j] = (short)f2bf(vv[j] - bf2f(h));
            }
            const int off = (s * BPB + b) * 8;
            *reinterpret_cast<short8*>(&x_hi[off]) = hv;
            *reinterpret_cast<short8*>(&x_lo[off]) = lv;
        }
    }
    __syncthreads();

    // per-lane operand bases: A(W): g0,g2->hi, g1->lo, g3->zero;
    //                         B(X): g0,g1->hi, g2->lo, g3->zero.
    const unsigned short* wbase = (q == 1) ? w_lo : ((q == 3) ? zpad : w_hi);
    const unsigned short* xbase = (q == 2) ? x_lo : ((q == 3) ? zpad : x_hi);
    const int msk = (q == 3) ? 0 : 1;
    const int b   = bg0 + 16 * wv + em;      // this lane's batch row

    cg::grid_group grid = cg::this_grid();

    #pragma unroll 1
    for (int it = 0; it < 3; ++it) {
        // hoist v[b, o, 4q..4q+3] (written by squash of previous iteration)
        f32x4 vreg[OO];
        if (it > 0) {
            #pragma unroll
            for (int o = 0; o < OO; ++o) {
                const float4 t = *reinterpret_cast<const float4*>(
                    V + (size_t)b * (OO * EE) + o * EE + 4 * q);
                vreg[o] = (f32x4){t.x, t.y, t.z, t.w};
            }
        }

        f32x4 sacc[OO];
        #pragma unroll
        for (int o = 0; o < OO; ++o) sacc[o] = (f32x4){0.f, 0.f, 0.f, 0.f};

        #pragma unroll 1
        for (int s = 0; s < CHUNK; ++s) {
            const short8 xf = *reinterpret_cast<const short8*>(
                xbase + msk * ((s * BPB + 16 * wv + em) * 8));
            f32x4 u[OO];
            #pragma unroll
            for (int o = 0; o < OO; ++o) {
                const short8 wf = *reinterpret_cast<const short8*>(
                    wbase + msk * ((s * 160 + o * 16 + em) * 8));
                u[o] = __builtin_amdgcn_mfma_f32_16x16x32_bf16(
                           wf, xf, (f32x4){0.f, 0.f, 0.f, 0.f}, 0, 0, 0);
            }
            if (it > 0) {
                float elg[OO];
                float den = 0.f;
                #pragma unroll
                for (int o = 0; o < OO; ++o) {
                    float t = u[o][0]*vreg[o][0] + u[o][1]*vreg[o][1]
                            + u[o][2]*vreg[o][2] + u[o][3]*vreg[o][3];
                    t += __shfl_xor(t, 16);     // fold q-groups: full sum over e
                    t += __shfl_xor(t, 32);
                    elg[o] = __expf(t);         // bounded logits (r1-r10)
                    den += elg[o];
                }
                const float rden = __fdividef(1.0f, den);
                #pragma unroll
                for (int o = 0; o < OO; ++o)
                    sacc[o] += u[o] * (elg[o] * rden);
            } else {
                #pragma unroll
                for (int o = 0; o < OO; ++o) sacc[o] += u[o];
            }
        }

        // write partial s: direct float4 stores (64B-granular; no LDS
        // transpose -- W/x must stay resident in LDS)
        {
            const float mul = (it == 0) ? 0.1f : 1.0f;
            float* sp = s_part + (((size_t)cx * BATCH + b) * OO) * EE + 4 * q;
            #pragma unroll
            for (int o = 0; o < OO; ++o) {
                const f32x4 t = sacc[o];
                float4 w4;
                w4.x = mul * t[0]; w4.y = mul * t[1];
                w4.z = mul * t[2]; w4.w = mul * t[3];
                *reinterpret_cast<float4*>(sp + o * EE) = w4;
            }
        }
        __threadfence();
        grid.sync();

        // squash on 80 blocks: reduce chunks, squash, update V / write out
        if (bid < (BATCH * OO * EE) / NT) {      // 80 blocks
            const int g = bid * NT + tid;        // < 40960
            const float* spp = s_part + g;
            float ssum = 0.f;
            #pragma unroll 8
            for (int ch = 0; ch < NCHUNK; ++ch)
                ssum += spp[(size_t)ch * (BATCH * OO * EE)];
            float sq = ssum * ssum;
            #pragma unroll
            for (int m = 1; m < 16; m <<= 1) sq += __shfl_xor(sq, m, 16);
            const float scale = sq / (1.f + sq) / (sqrtf(sq) + 1e-6f);
            const float v = scale * ssum;
            if (it == 0)      V[g] = v;
            else if (it == 1) V[g] += v;
            else              out[g] = v;
        }
        if (it < 2) { __threadfence(); grid.sync(); }
    }
}

extern "C" void kernel_launch(void* const* d_in, const int* in_sizes, int n_in,
                              void* d_out, int out_size, void* d_ws, size_t ws_size,
                              hipStream_t stream) {
    const float* x = (const float*)d_in[0];   // [256,32,6,6,8]
    const float* W = (const float*)d_in[1];   // [1,32,6,6,10,8,16]
    float* out = (float*)d_out;               // [256,10,16]

    float* s_part = (float*)d_ws;                                   // NCHUNK*40960 floats
    float* V      = s_part + (size_t)NCHUNK * BATCH * OO * EE;      // 40960 floats

    hipFuncSetAttribute(reinterpret_cast<const void*>(caps_mega_kernel),
                        hipFuncAttributeMaxDynamicSharedMemorySize, SMEM_BYTES);

    void* args[] = {(void*)&x, (void*)&W, (void*)&V, (void*)&s_part, (void*)&out};
    hipLaunchCooperativeKernel(reinterpret_cast<void*>(caps_mega_kernel),
                               dim3(NCHUNK, NBP), dim3(NT),
                               args, SMEM_BYTES, stream);
}

// Round 12
// 219.178 us; speedup vs baseline: 2.9031x; 2.9031x over previous
//
#include <hip/hip_runtime.h>
#include <math.h>

// Problem constants
#define BATCH 256
#define IC    1152   // 32*6*6 input capsule positions
#define DD    8
#define OO    10
#define EE    16
#define BTILE 64     // batches per block (wave w owns rows 16w..16w+15)
#define NBT   4      // BATCH / BTILE
#define NT    256    // 4 waves
#define CHUNK 8      // ijk per block
#define NCHUNK 144   // IC / CHUNK
#define WPC   1280   // OO*DD*EE floats of W per ijk
#define WHALF ((size_t)IC * WPC)          // shorts per W half-buffer

typedef __attribute__((ext_vector_type(8))) short short8;  // 8 bf16 (4 VGPR)
typedef __attribute__((ext_vector_type(4))) float f32x4;   // MFMA C/D

__device__ __forceinline__ unsigned short f2bf(float f) {  // RNE fp32->bf16
    unsigned u = __float_as_uint(f);
    unsigned r = u + 0x7FFFu + ((u >> 16) & 1u);
    return (unsigned short)(r >> 16);
}
__device__ __forceinline__ float bf2f(unsigned short h) {
    return __uint_as_float(((unsigned)h) << 16);
}

// prep: convert W fp32 -> bf16 hi/lo ONCE, into the exact MFMA feed layout
// [ijk][o*16+e][d] (so pass-kernel loads are plain per-lane short8).
// Also writes the 16B zero page used by k-group q=3.
__global__ __launch_bounds__(256) void caps_prep_kernel(
    const float* __restrict__ W,            // [1152][10][8][16]
    unsigned short* __restrict__ w_hi,
    unsigned short* __restrict__ w_lo,
    unsigned short* __restrict__ wz)
{
    const int idx = blockIdx.x * 256 + threadIdx.x;   // < 184320 = 1152*160
    if (blockIdx.x == 0 && threadIdx.x < 8) wz[threadIdx.x] = 0;
    const int ijk = idx / 160;
    const int oe  = idx - ijk * 160;
    const int o = oe >> 4, e = oe & 15;
    const float* src = W + (size_t)ijk * WPC + o * 128 + e;   // stride 16 over d
    short8 hv, lv;
    #pragma unroll
    for (int d = 0; d < 8; ++d) {
        const float f = src[d * 16];
        const unsigned short h = f2bf(f);
        hv[d] = (short)h;
        lv[d] = (short)f2bf(f - bf2f(h));
    }
    *reinterpret_cast<short8*>(w_hi + (size_t)idx * 8) = hv;
    *reinterpret_cast<short8*>(w_lo + (size_t)idx * 8) = lv;
}

// MFMA pass kernel (r10 math, HW-verified bit-exact), restructured:
//  - W read DIRECTLY from prepped global bf16 (no W LDS, no convert/scatter):
//    per instr lanes 0-15 read 256B contiguous (hi), 16-31 contiguous (lo),
//    32-47 duplicate hi, 48-63 hit the zero page -> ~9 lines/instr, VMEM-
//    pipelined; W bf16 total 5.9MB -> L2-resident.
//  - Register diet: routing passes do TWO MFMA sweeps per (s): sweep1 makes
//    elg[10] (u transient), sweep2 recomputes u and accumulates sacc. Live
//    ~115 regs (vreg40+sacc40+elg10+transients). launch_bounds(256,4) caps
//    VGPR at 128 (cap > live, unlike r1-r3) -> 16 waves/CU.
//  - LDS: x hi/lo (in-pass converted; cheap: 2 units/thread) + zpad = 16.4KB.
//  - epilogue: direct float4 stores (per-instr: 16 full 64B lines).
//  Checks: WRITE_SIZE ~21.2MB/pass (no spill), VGPR<=128.
__global__ __launch_bounds__(NT, 4) void caps_pass_kernel(
    const float* __restrict__ x,            // [256][1152][8]
    const unsigned short* __restrict__ w_hi,
    const unsigned short* __restrict__ w_lo,
    const unsigned short* __restrict__ wz,  // 16B zeros
    const float* __restrict__ V,            // [256][10][16]
    float* __restrict__ s_part,             // [NCHUNK][256][10][16]
    int first)
{
    __shared__ unsigned short x_hi[CHUNK][BTILE][8];   // 8 KB
    __shared__ unsigned short x_lo[CHUNK][BTILE][8];   // 8 KB
    __shared__ unsigned short zpad[8];                 // 16 B

    const int tid  = threadIdx.x;
    const int wv   = tid >> 6;
    const int lane = tid & 63;
    const int q    = lane >> 4;    // k-group (0..3)
    const int em   = lane & 15;    // A-row (e) / B-col (b-local)
    const int ijk0 = blockIdx.x * CHUNK;
    const int bg0  = blockIdx.y * BTILE;

    if (tid < 8) zpad[tid] = 0;

    // ---- stage x chunk -> bf16 hi/lo, layout [s][b][d] (r10-verified) ----
    #pragma unroll
    for (int i = 0; i < 2; ++i) {
        const int u = tid + i * NT;            // 0..511 = (b,s)
        const int b = u >> 3, s = u & 7;
        const float* xp = x + ((size_t)(bg0 + b) * IC + (ijk0 + s)) * DD;
        const float4 xa = *reinterpret_cast<const float4*>(xp);
        const float4 xb = *reinterpret_cast<const float4*>(xp + 4);
        const float vv[8] = {xa.x,xa.y,xa.z,xa.w, xb.x,xb.y,xb.z,xb.w};
        short8 hv, lv;
        #pragma unroll
        for (int j = 0; j < 8; ++j) {
            const unsigned short h = f2bf(vv[j]);
            hv[j] = (short)h;
            lv[j] = (short)f2bf(vv[j] - bf2f(h));
        }
        *reinterpret_cast<short8*>(&x_hi[s][b][0]) = hv;
        *reinterpret_cast<short8*>(&x_lo[s][b][0]) = lv;
    }

    // hoist v[b, o, e=4q..4q+3] into 10 float4 regs (routing passes only)
    f32x4 vreg[OO];
    const int b = bg0 + 16 * wv + em;
    if (!first) {
        #pragma unroll
        for (int o = 0; o < OO; ++o) {
            const float4 t = *reinterpret_cast<const float4*>(
                V + (size_t)b * (OO * EE) + o * EE + 4 * q);
            vreg[o] = (f32x4){t.x, t.y, t.z, t.w};
        }
    }
    __syncthreads();

    // per-lane operand bases (r10-verified packing):
    //   A(W): q0,q2 -> hi, q1 -> lo, q3 -> zero page (global)
    //   B(X): q0,q1 -> hi, q2 -> lo, q3 -> zpad (LDS)
    const unsigned short* wbase = (q == 1) ? w_lo : ((q == 3) ? wz : w_hi);
    const unsigned short* xbase = (q == 2) ? &x_lo[0][0][0]
                                : ((q == 3) ? zpad : &x_hi[0][0][0]);
    const size_t wmsk = (q == 3) ? 0 : 1;
    const int    xmsk = (q == 3) ? 0 : 1;

    // opaque copy of wbase for the second sweep: defeats load-CSE so u from
    // sweep1 is NOT kept alive across the softmax (the register diet).
    uintptr_t wb2i = (uintptr_t)wbase;
    asm volatile("" : "+v"(wb2i));
    const unsigned short* wbase2 = (const unsigned short*)wb2i;

    f32x4 sacc[OO];
    #pragma unroll
    for (int o = 0; o < OO; ++o) sacc[o] = (f32x4){0.f, 0.f, 0.f, 0.f};

    #pragma unroll 1
    for (int s = 0; s < CHUNK; ++s) {
        const short8 xf = *reinterpret_cast<const short8*>(
            xbase + xmsk * ((s * BTILE + 16 * wv + em) * 8));
        const size_t woff = (size_t)(ijk0 + s) * WPC + (size_t)em * 8;

        if (!first) {
            // sweep 1: logits only (u transient)
            float elg[OO];
            float den = 0.f;
            #pragma unroll
            for (int o = 0; o < OO; ++o) {
                const short8 wf = *reinterpret_cast<const short8*>(
                    wbase + wmsk * (woff + o * 128));
                const f32x4 u = __builtin_amdgcn_mfma_f32_16x16x32_bf16(
                                    wf, xf, (f32x4){0.f,0.f,0.f,0.f}, 0, 0, 0);
                float t = u[0]*vreg[o][0] + u[1]*vreg[o][1]
                        + u[2]*vreg[o][2] + u[3]*vreg[o][3];
                t += __shfl_xor(t, 16);     // fold q-groups: full sum over e
                t += __shfl_xor(t, 32);
                elg[o] = __expf(t);         // bounded logits (r1-r10)
                den += elg[o];
            }
            const float rden = __fdividef(1.0f, den);
            // sweep 2: recompute u, accumulate
            #pragma unroll
            for (int o = 0; o < OO; ++o) {
                const short8 wf = *reinterpret_cast<const short8*>(
                    wbase2 + wmsk * (woff + o * 128));
                const f32x4 u = __builtin_amdgcn_mfma_f32_16x16x32_bf16(
                                    wf, xf, (f32x4){0.f,0.f,0.f,0.f}, 0, 0, 0);
                sacc[o] += u * (elg[o] * rden);
            }
        } else {
            #pragma unroll
            for (int o = 0; o < OO; ++o) {
                const short8 wf = *reinterpret_cast<const short8*>(
                    wbase + wmsk * (woff + o * 128));
                const f32x4 u = __builtin_amdgcn_mfma_f32_16x16x32_bf16(
                                    wf, xf, (f32x4){0.f,0.f,0.f,0.f}, 0, 0, 0);
                sacc[o] += u;
            }
        }
    }

    // direct float4 stores: per instr 16 batches x (4q covering one 64B line)
    {
        const float mul = first ? 0.1f : 1.0f;   // uniform c=0.1 folded here
        float* sp = s_part + (((size_t)blockIdx.x * BATCH + b) * OO) * EE + 4 * q;
        #pragma unroll
        for (int o = 0; o < OO; ++o) {
            const f32x4 t = sacc[o];
            float4 w4;
            w4.x = mul * t[0]; w4.y = mul * t[1];
            w4.z = mul * t[2]; w4.w = mul * t[3];
            *reinterpret_cast<float4*>(sp + o * EE) = w4;
        }
    }
}

// squash v2: 1024 threads, 16-way chunk split (9 fully-unrolled strided
// loads/thread all in flight) + LDS tree; wave 0 squashes + stores.
__global__ __launch_bounds__(1024) void caps_squash_kernel(
    const float* __restrict__ s_part,  // [NCHUNK][256][10][16]
    float* __restrict__ V,             // [256][10][16]
    float* __restrict__ out,           // [256][10][16]
    int accum, int last)
{
    __shared__ float red[15][64];
    const int lane = threadIdx.x & 63;
    const int w    = threadIdx.x >> 6;          // 0..15
    const int g    = blockIdx.x * 64 + lane;    // < 40960

    const float* sp = s_part + g;
    float s = 0.f;
    #pragma unroll
    for (int i = 0; i < NCHUNK / 16; ++i)       // 9 loads, all outstanding
        s += sp[(size_t)(w * (NCHUNK / 16) + i) * (BATCH * OO * EE)];

    if (w > 0) red[w - 1][lane] = s;
    __syncthreads();
    if (w == 0) {
        #pragma unroll
        for (int i = 0; i < 15; ++i) s += red[i][lane];

        // squared norm over the 16-element e axis (lanes g..g+15 share (b,o))
        float sq = s * s;
        #pragma unroll
        for (int m = 1; m < 16; m <<= 1) sq += __shfl_xor(sq, m, 16);

        const float scale = sq / (1.f + sq) / (sqrtf(sq) + 1e-6f);
        const float v = scale * s;

        if (last)       out[g] = v;
        else if (accum) V[g]  += v;
        else            V[g]   = v;
    }
}

extern "C" void kernel_launch(void* const* d_in, const int* in_sizes, int n_in,
                              void* d_out, int out_size, void* d_ws, size_t ws_size,
                              hipStream_t stream) {
    const float* x = (const float*)d_in[0];   // [256,32,6,6,8]
    const float* W = (const float*)d_in[1];   // [1,32,6,6,10,8,16]
    float* out = (float*)d_out;               // [256,10,16]

    float* s_part = (float*)d_ws;                                   // 144*40960 floats
    float* V      = s_part + (size_t)NCHUNK * BATCH * OO * EE;      // 40960 floats
    unsigned short* w_hi = (unsigned short*)(V + BATCH * OO * EE);
    unsigned short* w_lo = w_hi + WHALF;
    unsigned short* wz   = w_lo + WHALF;                            // 16B zeros

    dim3 grid(NCHUNK, NBT), blk(NT);
    const int sq_blocks = (BATCH * OO * EE) / 64;   // 640

    // one-time W conversion (runs per call; ~6us, replaces 3x convert+scatter)
    caps_prep_kernel<<<(IC * 160) / 256, 256, 0, stream>>>(W, w_hi, w_lo, wz);

    // iteration 1: b=0 -> c uniform 0.1; v1 -> V
    caps_pass_kernel<<<grid, blk, 0, stream>>>(x, w_hi, w_lo, wz, V, s_part, 1);
    caps_squash_kernel<<<sq_blocks, 1024, 0, stream>>>(s_part, V, out, 0, 0);
    // iteration 2: logits = dot(u_hat, v1); V += v2
    caps_pass_kernel<<<grid, blk, 0, stream>>>(x, w_hi, w_lo, wz, V, s_part, 0);
    caps_squash_kernel<<<sq_blocks, 1024, 0, stream>>>(s_part, V, out, 1, 0);
    // iteration 3 (final): logits = dot(u_hat, v1+v2); output v3
    caps_pass_kernel<<<grid, blk, 0, stream>>>(x, w_hi, w_lo, wz, V, s_part, 0);
    caps_squash_kernel<<<sq_blocks, 1024, 0, stream>>>(s_part, V, out, 0, 1);
}

// Round 13
// 152.804 us; speedup vs baseline: 4.1642x; 1.4344x over previous
//
#include <hip/hip_runtime.h>
#include <math.h>

// Problem constants
#define BATCH 256
#define IC    1152   // 32*6*6 input capsule positions
#define DD    8
#define OO    10
#define EE    16
#define BTILE 64     // batches per block (wave w owns rows 16w..16w+15)
#define NBT   4      // BATCH / BTILE
#define NT    256    // 4 waves
#define CHUNK 6      // ijk per block
#define NCHUNK 192   // IC / CHUNK
#define WPC   1280   // OO*DD*EE floats of W per ijk
#define WHALF ((size_t)IC * 160 * 8)      // shorts per W half-buffer

typedef __attribute__((ext_vector_type(8))) short short8;  // 8 bf16 (4 VGPR)
typedef __attribute__((ext_vector_type(4))) float f32x4;   // MFMA C/D

__device__ __forceinline__ unsigned short f2bf(float f) {  // RNE fp32->bf16
    unsigned u = __float_as_uint(f);
    unsigned r = u + 0x7FFFu + ((u >> 16) & 1u);
    return (unsigned short)(r >> 16);
}
__device__ __forceinline__ float bf2f(unsigned short h) {
    return __uint_as_float(((unsigned)h) << 16);
}

// prep: convert W fp32 -> bf16 hi/lo ONCE into the MFMA feed layout
// [ijk][o*16+e][d]. Verified bit-compatible in r12 (absmax unchanged).
__global__ __launch_bounds__(256) void caps_prep_kernel(
    const float* __restrict__ W,            // [1152][10][8][16]
    unsigned short* __restrict__ w_hi,
    unsigned short* __restrict__ w_lo)
{
    const int idx = blockIdx.x * 256 + threadIdx.x;   // < 184320 = 1152*160
    const int ijk = idx / 160;
    const int oe  = idx - ijk * 160;
    const int o = oe >> 4, e = oe & 15;
    const float* src = W + (size_t)ijk * WPC + o * 128 + e;   // stride 16 over d
    short8 hv, lv;
    #pragma unroll
    for (int d = 0; d < 8; ++d) {
        const float f = src[d * 16];
        const unsigned short h = f2bf(f);
        hv[d] = (short)h;
        lv[d] = (short)f2bf(f - bf2f(h));
    }
    *reinterpret_cast<short8*>(w_hi + (size_t)idx * 8) = hv;
    *reinterpret_cast<short8*>(w_lo + (size_t)idx * 8) = lv;
}

// MFMA pass kernel = r10's PROVEN main loop (single sweep, u[10] live,
// NO launch_bounds cap -- r1/r2/r3/r11/r12 all spilled the moment a
// min-waves bound was set; uncapped builds never spilled), fed by prepped
// global bf16 so W staging is a PURE LINEAR memcpy (960 float4/block, no
// convert, no scatter -- r10 burned ~400 VALU/thread + 80 b16 scatters here).
// CHUNK=6 -> LDS 43 KB -> 3 blocks/CU by LDS; grid 768 = 3/CU exactly.
// MFMA packing (r10/r12 HW-verified): lane-group q supplies k=8q..8q+7;
// A={Wh,Wl,Wh,0}[q], B={Xh,Xh,Xl,0}[q]; D: col=lane&15=b, row=4q+reg=e.
//  Checks: VGPR 140-180 (not 32-64!), WRITE_SIZE ~31.7 MB (s_part only).
__global__ __launch_bounds__(NT) void caps_pass_kernel(
    const float* __restrict__ x,            // [256][1152][8]
    const unsigned short* __restrict__ w_hi,
    const unsigned short* __restrict__ w_lo,
    const float* __restrict__ V,            // [256][10][16]
    float* __restrict__ s_part,             // [NCHUNK][256][10][16]
    int first)
{
    __shared__ unsigned short wl_hi[CHUNK * 160 * 8];   // 15 KB
    __shared__ unsigned short wl_lo[CHUNK * 160 * 8];   // 15 KB
    __shared__ unsigned short x_hi[CHUNK][BTILE][8];    // 6 KB
    __shared__ unsigned short x_lo[CHUNK][BTILE][8];    // 6 KB
    __shared__ unsigned short zpad[8];                  // 16 B

    const int tid  = threadIdx.x;
    const int wv   = tid >> 6;
    const int lane = tid & 63;
    const int q    = lane >> 4;    // k-group (0..3)
    const int em   = lane & 15;    // A-row (e) / B-col (b-local)
    const int ijk0 = blockIdx.x * CHUNK;
    const int bg0  = blockIdx.y * BTILE;

    if (tid < 8) zpad[tid] = 0;

    // ---- stage W chunk: pure linear float4 copy from prepped global ----
    {
        const float4* sh = reinterpret_cast<const float4*>(w_hi + (size_t)ijk0 * 160 * 8);
        const float4* sl = reinterpret_cast<const float4*>(w_lo + (size_t)ijk0 * 160 * 8);
        float4* dh = reinterpret_cast<float4*>(wl_hi);
        float4* dl = reinterpret_cast<float4*>(wl_lo);
        #pragma unroll
        for (int i = 0; i < 4; ++i) {           // 4*256 >= 960 units
            const int f = tid + i * NT;
            if (f < CHUNK * 160) { dh[f] = sh[f]; dl[f] = sl[f]; }
        }
    }
    // ---- stage x chunk -> bf16 hi/lo, layout [s][b][d] (r10-verified) ----
    {
        #pragma unroll
        for (int i = 0; i < 2; ++i) {
            const int u = tid + i * NT;          // 0..511, need < 384
            if (u < CHUNK * BTILE) {
                const int b = u / CHUNK, s = u - b * CHUNK;  // s fastest: coalesced
                const float* xp = x + ((size_t)(bg0 + b) * IC + (ijk0 + s)) * DD;
                const float4 xa = *reinterpret_cast<const float4*>(xp);
                const float4 xb = *reinterpret_cast<const float4*>(xp + 4);
                const float vv[8] = {xa.x,xa.y,xa.z,xa.w, xb.x,xb.y,xb.z,xb.w};
                short8 hv, lv;
                #pragma unroll
                for (int j = 0; j < 8; ++j) {
                    const unsigned short h = f2bf(vv[j]);
                    hv[j] = (short)h;
                    lv[j] = (short)f2bf(vv[j] - bf2f(h));
                }
                *reinterpret_cast<short8*>(&x_hi[s][b][0]) = hv;
                *reinterpret_cast<short8*>(&x_lo[s][b][0]) = lv;
            }
        }
    }

    // hoist v[b, o, e=4q..4q+3] into 10 float4 regs (routing passes only)
    f32x4 vreg[OO];
    const int b = bg0 + 16 * wv + em;
    if (!first) {
        #pragma unroll
        for (int o = 0; o < OO; ++o) {
            const float4 t = *reinterpret_cast<const float4*>(
                V + (size_t)b * (OO * EE) + o * EE + 4 * q);
            vreg[o] = (f32x4){t.x, t.y, t.z, t.w};
        }
    }
    __syncthreads();

    // per-lane operand bases (r10-verified packing):
    //   A(W): q0,q2 -> hi, q1 -> lo, q3 -> zpad
    //   B(X): q0,q1 -> hi, q2 -> lo, q3 -> zpad
    const unsigned short* wbase = (q == 1) ? wl_lo : ((q == 3) ? zpad : wl_hi);
    const unsigned short* xbase = (q == 2) ? &x_lo[0][0][0]
                                : ((q == 3) ? zpad : &x_hi[0][0][0]);
    const int msk = (q == 3) ? 0 : 1;

    f32x4 sacc[OO];
    #pragma unroll
    for (int o = 0; o < OO; ++o) sacc[o] = (f32x4){0.f, 0.f, 0.f, 0.f};

    #pragma unroll 1
    for (int s = 0; s < CHUNK; ++s) {
        const short8 xf = *reinterpret_cast<const short8*>(
            xbase + msk * ((s * BTILE + 16 * wv + em) * 8));
        f32x4 u[OO];
        #pragma unroll
        for (int o = 0; o < OO; ++o) {
            const short8 wf = *reinterpret_cast<const short8*>(
                wbase + msk * ((s * 160 + o * 16 + em) * 8));
            u[o] = __builtin_amdgcn_mfma_f32_16x16x32_bf16(
                       wf, xf, (f32x4){0.f, 0.f, 0.f, 0.f}, 0, 0, 0);
        }
        if (!first) {
            float elg[OO];
            float den = 0.f;
            #pragma unroll
            for (int o = 0; o < OO; ++o) {
                float t = u[o][0]*vreg[o][0] + u[o][1]*vreg[o][1]
                        + u[o][2]*vreg[o][2] + u[o][3]*vreg[o][3];
                t += __shfl_xor(t, 16);     // fold q-groups: full sum over e
                t += __shfl_xor(t, 32);
                elg[o] = __expf(t);         // bounded logits (r1-r12)
                den += elg[o];
            }
            const float rden = __fdividef(1.0f, den);
            #pragma unroll
            for (int o = 0; o < OO; ++o)
                sacc[o] += u[o] * (elg[o] * rden);
        } else {
            #pragma unroll
            for (int o = 0; o < OO; ++o) sacc[o] += u[o];
        }
    }

    // direct float4 stores: 4 q-groups fill each 64B line (r12-verified)
    {
        const float mul = first ? 0.1f : 1.0f;   // uniform c=0.1 folded here
        float* sp = s_part + (((size_t)blockIdx.x * BATCH + b) * OO) * EE + 4 * q;
        #pragma unroll
        for (int o = 0; o < OO; ++o) {
            const f32x4 t = sacc[o];
            float4 w4;
            w4.x = mul * t[0]; w4.y = mul * t[1];
            w4.z = mul * t[2]; w4.w = mul * t[3];
            *reinterpret_cast<float4*>(sp + o * EE) = w4;
        }
    }
}

// squash v2: 1024 threads, 16-way chunk split (12 strided loads/thread all
// in flight) + LDS tree; wave 0 squashes + stores.
__global__ __launch_bounds__(1024) void caps_squash_kernel(
    const float* __restrict__ s_part,  // [NCHUNK][256][10][16]
    float* __restrict__ V,             // [256][10][16]
    float* __restrict__ out,           // [256][10][16]
    int accum, int last)
{
    __shared__ float red[15][64];
    const int lane = threadIdx.x & 63;
    const int w    = threadIdx.x >> 6;          // 0..15
    const int g    = blockIdx.x * 64 + lane;    // < 40960

    const float* sp = s_part + g;
    float s = 0.f;
    #pragma unroll
    for (int i = 0; i < NCHUNK / 16; ++i)       // 12 loads, all outstanding
        s += sp[(size_t)(w * (NCHUNK / 16) + i) * (BATCH * OO * EE)];

    if (w > 0) red[w - 1][lane] = s;
    __syncthreads();
    if (w == 0) {
        #pragma unroll
        for (int i = 0; i < 15; ++i) s += red[i][lane];

        // squared norm over the 16-element e axis (lanes g..g+15 share (b,o))
        float sq = s * s;
        #pragma unroll
        for (int m = 1; m < 16; m <<= 1) sq += __shfl_xor(sq, m, 16);

        const float scale = sq / (1.f + sq) / (sqrtf(sq) + 1e-6f);
        const float v = scale * s;

        if (last)       out[g] = v;
        else if (accum) V[g]  += v;
        else            V[g]   = v;
    }
}

extern "C" void kernel_launch(void* const* d_in, const int* in_sizes, int n_in,
                              void* d_out, int out_size, void* d_ws, size_t ws_size,
                              hipStream_t stream) {
    const float* x = (const float*)d_in[0];   // [256,32,6,6,8]
    const float* W = (const float*)d_in[1];   // [1,32,6,6,10,8,16]
    float* out = (float*)d_out;               // [256,10,16]

    float* s_part = (float*)d_ws;                                   // 192*40960 floats
    float* V      = s_part + (size_t)NCHUNK * BATCH * OO * EE;      // 40960 floats
    unsigned short* w_hi = (unsigned short*)(V + BATCH * OO * EE);
    unsigned short* w_lo = w_hi + WHALF;
    // total ws use ~37.6 MB << 268 MB (fill-poison size observed r0-r12)

    dim3 grid(NCHUNK, NBT), blk(NT);
    const int sq_blocks = (BATCH * OO * EE) / 64;   // 640

    // one-time W conversion into MFMA feed layout (~5us)
    caps_prep_kernel<<<(IC * 160) / 256, 256, 0, stream>>>(W, w_hi, w_lo);

    // iteration 1: b=0 -> c uniform 0.1; v1 -> V
    caps_pass_kernel<<<grid, blk, 0, stream>>>(x, w_hi, w_lo, V, s_part, 1);
    caps_squash_kernel<<<sq_blocks, 1024, 0, stream>>>(s_part, V, out, 0, 0);
    // iteration 2: logits = dot(u_hat, v1); V += v2
    caps_pass_kernel<<<grid, blk, 0, stream>>>(x, w_hi, w_lo, V, s_part, 0);
    caps_squash_kernel<<<sq_blocks, 1024, 0, stream>>>(s_part, V, out, 1, 0);
    // iteration 3 (final): logits = dot(u_hat, v1+v2); output v3
    caps_pass_kernel<<<grid, blk, 0, stream>>>(x, w_hi, w_lo, V, s_part, 0);
    caps_squash_kernel<<<sq_blocks, 1024, 0, stream>>>(s_part, V, out, 0, 1);
}